// Round 1
// baseline (232.438 us; speedup 1.0000x reference)
//
#include <hip/hip_runtime.h>
#include <hip/hip_bf16.h>

typedef __attribute__((ext_vector_type(8))) short short8;
typedef __attribute__((ext_vector_type(4))) float f32x4;
using u16 = unsigned short;
using u32 = unsigned int;

#define IN_F 4096
#define OUT_F 4096
#define RANK 128
#define M_TOK 128  // B*S = 8*16

// ---- bf16 pack helpers ----
// ints in [-8,7] are exact in bf16: truncating pack is lossless
__device__ inline u32 packi(int a, int b) {
    float fa = (float)a, fb = (float)b;
    return (__builtin_bit_cast(u32, fa) >> 16) |
           (__builtin_bit_cast(u32, fb) & 0xFFFF0000u);
}
// round-to-nearest-even f32 -> bf16 pair
__device__ inline u32 packf(float a, float b) {
    u32 ua = __builtin_bit_cast(u32, a);
    u32 ub = __builtin_bit_cast(u32, b);
    ua = (ua + 0x7FFFu + ((ua >> 16) & 1u)) >> 16;
    ub = (ub + 0x7FFFu + ((ub >> 16) & 1u));
    return ua | (ub & 0xFFFF0000u);
}
__device__ inline u16 f2bf(float f) {
    u32 u = __builtin_bit_cast(u32, f);
    u = (u + 0x7FFFu + ((u >> 16) & 1u)) >> 16;
    return (u16)u;
}

// ws layout: [0,64KB) y fp32 | [64KB, +1MB) x_bf16 | [+1MB, +1MB) Bt bf16
#define WS_Y 0
#define WS_XB 65536
#define WS_BT (65536 + 1048576)

__global__ __launch_bounds__(256) void zero_y_kernel(float* __restrict__ y) {
    int i = blockIdx.x * 256 + threadIdx.x;  // grid 16*256 = 4096 float4
    f32x4 z = {0.f, 0.f, 0.f, 0.f};
    reinterpret_cast<f32x4*>(y)[i] = z;
}

// blocks 0..1023: y = x@A partial (8 mt x 8 rt x 16 ks), also x->bf16 on rt==0
// blocks 1024..1151: B -> Bt bf16 transpose
__global__ __launch_bounds__(256) void prep_kernel(
    const float* __restrict__ x, const float* __restrict__ A,
    const float* __restrict__ B, float* __restrict__ y,
    u16* __restrict__ xb, u16* __restrict__ bt) {
    int bid = blockIdx.x;
    int tid = threadIdx.x;
    if (bid < 1024) {
        int mt = bid >> 7;
        int rt = (bid >> 4) & 7;
        int ks = bid & 15;
        int m0 = mt * 16, r0 = rt * 16, k0 = ks * 256;
        __shared__ float xs[16 * 256];
        for (int u = tid; u < 1024; u += 256) {
            int row = u >> 6, c4 = u & 63;
            f32x4 v = *reinterpret_cast<const f32x4*>(
                &x[(size_t)(m0 + row) * IN_F + k0 + c4 * 4]);
            *reinterpret_cast<f32x4*>(&xs[row * 256 + c4 * 4]) = v;
        }
        __syncthreads();
        if (rt == 0) {
            for (int u = tid; u < 4096; u += 256) {
                int row = u >> 8, c = u & 255;
                xb[(size_t)(m0 + row) * IN_F + k0 + c] = f2bf(xs[row * 256 + c]);
            }
        }
        int ml = tid >> 4;
        int r = r0 + (tid & 15);
        const float* ap = A + (size_t)k0 * RANK + r;
        const float* xr = xs + ml * 256;
        float acc = 0.f;
        #pragma unroll 8
        for (int k = 0; k < 256; ++k) {
            acc = fmaf(xr[k], ap[(size_t)k * RANK], acc);
        }
        atomicAdd(&y[(m0 + ml) * RANK + r], acc);
    } else {
        int o0 = (bid - 1024) * 32;
        for (int u = tid; u < 32 * RANK; u += 256) {
            int o = o0 + (u & 31), r = u >> 5;
            bt[(size_t)o * RANK + r] = f2bf(B[(size_t)r * OUT_F + o]);
        }
    }
}

// grid 128 blocks (one per 32-output tile), 512 threads = 8 waves
// wave (wm 0..3, wn 0..1): 2 m-tiles (16x16 each) x 1 n-tile
__global__ __launch_bounds__(512) void main_kernel(
    const u16* __restrict__ xb, const int* __restrict__ wq,
    const float* __restrict__ scale, const float* __restrict__ bias,
    const float* __restrict__ y, const u16* __restrict__ bt,
    float* __restrict__ out) {
    int tid = threadIdx.x;
    int lane = tid & 63;
    int wid = tid >> 6;
    int wm = wid >> 1;
    int wn = wid & 1;
    int col = lane & 15;
    int kg = lane >> 4;  // 0..3, k-chunk = kg*8
    int o = blockIdx.x * 32 + wn * 16 + col;
    int m0 = wm * 32 + col;  // A-operand row (tile 0); tile 1 = +16

    const int* wp = wq + (size_t)o * IN_F + kg * 8;
    const u16* xp0 = xb + (size_t)m0 * IN_F + kg * 8;
    const u16* xp1 = xp0 + (size_t)16 * IN_F;

    f32x4 acc0 = {0.f, 0.f, 0.f, 0.f};
    f32x4 acc1 = {0.f, 0.f, 0.f, 0.f};

    for (int k = 0; k < IN_F; k += 128) {
        #pragma unroll
        for (int kk = 0; kk < 128; kk += 32) {
            const int* w = wp + k + kk;
            int4 wa = *reinterpret_cast<const int4*>(w);
            int4 wb = *reinterpret_cast<const int4*>(w + 4);
            union { u32 u[4]; short8 s8; } bf;
            bf.u[0] = packi(wa.x, wa.y);
            bf.u[1] = packi(wa.z, wa.w);
            bf.u[2] = packi(wb.x, wb.y);
            bf.u[3] = packi(wb.z, wb.w);
            short8 a0 = *reinterpret_cast<const short8*>(xp0 + k + kk);
            short8 a1 = *reinterpret_cast<const short8*>(xp1 + k + kk);
            acc0 = __builtin_amdgcn_mfma_f32_16x16x32_bf16(a0, bf.s8, acc0, 0, 0, 0);
            acc1 = __builtin_amdgcn_mfma_f32_16x16x32_bf16(a1, bf.s8, acc1, 0, 0, 0);
        }
    }

    // scale the quantized-GEMM part
    float s = scale[o];
    #pragma unroll
    for (int j = 0; j < 4; ++j) { acc0[j] *= s; acc1[j] *= s; }

    // LoRA: acc += y(m,r) @ Bt(o,r)^T over rank 128
    const float* yp0 = y + m0 * RANK + kg * 8;
    const float* yp1 = yp0 + 16 * RANK;
    const u16* bp = bt + (size_t)o * RANK + kg * 8;
    #pragma unroll
    for (int ks = 0; ks < RANK; ks += 32) {
        f32x4 ya = *reinterpret_cast<const f32x4*>(yp0 + ks);
        f32x4 yb = *reinterpret_cast<const f32x4*>(yp0 + ks + 4);
        f32x4 yc = *reinterpret_cast<const f32x4*>(yp1 + ks);
        f32x4 yd = *reinterpret_cast<const f32x4*>(yp1 + ks + 4);
        union { u32 u[4]; short8 s8; } af0, af1;
        af0.u[0] = packf(ya[0], ya[1]);
        af0.u[1] = packf(ya[2], ya[3]);
        af0.u[2] = packf(yb[0], yb[1]);
        af0.u[3] = packf(yb[2], yb[3]);
        af1.u[0] = packf(yc[0], yc[1]);
        af1.u[1] = packf(yc[2], yc[3]);
        af1.u[2] = packf(yd[0], yd[1]);
        af1.u[3] = packf(yd[2], yd[3]);
        short8 bfr = *reinterpret_cast<const short8*>(bp + ks);
        acc0 = __builtin_amdgcn_mfma_f32_16x16x32_bf16(af0.s8, bfr, acc0, 0, 0, 0);
        acc1 = __builtin_amdgcn_mfma_f32_16x16x32_bf16(af1.s8, bfr, acc1, 0, 0, 0);
    }

    float bv = bias[o];
    int rbase = wm * 32 + kg * 4;  // C/D row = (lane>>4)*4 + j
    float* op = out + (size_t)rbase * OUT_F + o;
    #pragma unroll
    for (int j = 0; j < 4; ++j) {
        op[(size_t)j * OUT_F] = acc0[j] + bv;
        op[(size_t)(j + 16) * OUT_F] = acc1[j] + bv;
    }
}

extern "C" void kernel_launch(void* const* d_in, const int* in_sizes, int n_in,
                              void* d_out, int out_size, void* d_ws, size_t ws_size,
                              hipStream_t stream) {
    const float* x = (const float*)d_in[0];
    const int* wq = (const int*)d_in[1];
    const float* scale = (const float*)d_in[2];
    const float* A = (const float*)d_in[3];
    const float* B = (const float*)d_in[4];
    const float* bias = (const float*)d_in[5];
    float* out = (float*)d_out;

    char* ws = (char*)d_ws;
    float* y = (float*)(ws + WS_Y);
    u16* xb = (u16*)(ws + WS_XB);
    u16* bt = (u16*)(ws + WS_BT);

    zero_y_kernel<<<16, 256, 0, stream>>>(y);
    prep_kernel<<<1152, 256, 0, stream>>>(x, A, B, y, xb, bt);
    main_kernel<<<128, 512, 0, stream>>>(xb, wq, scale, bias, y, bt, out);
}

// Round 3
// 146.939 us; speedup vs baseline: 1.5819x; 1.5819x over previous
//
#include <hip/hip_runtime.h>
#include <hip/hip_bf16.h>

typedef __attribute__((ext_vector_type(8))) short short8;
typedef __attribute__((ext_vector_type(4))) float f32x4;
using u16 = unsigned short;
using u32 = unsigned int;

#define IN_F 4096
#define OUT_F 4096
#define RANK 128
#define M_TOK 128  // B*S

typedef const __attribute__((address_space(1))) int* gas_ptr;
typedef __attribute__((address_space(3))) int* las_ptr;

// ---- bf16 pack helpers ----
__device__ inline u32 packi(int a, int b) {  // exact for [-8,7]
    float fa = (float)a, fb = (float)b;
    return (__builtin_bit_cast(u32, fa) >> 16) |
           (__builtin_bit_cast(u32, fb) & 0xFFFF0000u);
}
__device__ inline u32 packf(float a, float b) {  // RNE f32->bf16 pair
    u32 ua = __builtin_bit_cast(u32, a);
    u32 ub = __builtin_bit_cast(u32, b);
    ua = (ua + 0x7FFFu + ((ua >> 16) & 1u)) >> 16;
    ub = (ub + 0x7FFFu + ((ub >> 16) & 1u));
    return ua | (ub & 0xFFFF0000u);
}
__device__ inline u16 f2bf(float f) {
    u32 u = __builtin_bit_cast(u32, f);
    u = (u + 0x7FFFu + ((u >> 16) & 1u)) >> 16;
    return (u16)u;
}

// ws layout: y 64KB | xb 1MB | bt 1MB | at 1MB  (total ~3.06MB)
#define WS_Y 0
#define WS_XB 65536
#define WS_BT (WS_XB + 1048576)
#define WS_AT (WS_BT + 1048576)

// ---- prep0: [0,256) x->bf16 | [256,512) A^T bf16 | [512,768) B^T bf16
//             [768,1296) zero out + y
__global__ __launch_bounds__(256) void prep0_kernel(
    const float* __restrict__ x, const float* __restrict__ A,
    const float* __restrict__ B, float* __restrict__ outz,
    float* __restrict__ y, u16* __restrict__ xb,
    u16* __restrict__ at, u16* __restrict__ bt) {
    __shared__ float tile[64 * 33];
    int bid = blockIdx.x, tid = threadIdx.x;
    if (bid < 256) {
        // 256 blocks x 256 thr x 2 float4 = 131072 float4 = 524288 floats ✓
        const f32x4* xv = (const f32x4*)x;
        int vi = bid * 512 + tid * 2;
        f32x4 a = xv[vi], b = xv[vi + 1];
        union { u32 u[4]; short8 s; } p;
        p.u[0] = packf(a[0], a[1]); p.u[1] = packf(a[2], a[3]);
        p.u[2] = packf(b[0], b[1]); p.u[3] = packf(b[2], b[3]);
        *(short8*)(xb + (size_t)vi * 4) = p.s;
    } else if (bid < 512) {
        int b2 = bid - 256, kt = b2 >> 2, rt = b2 & 3;
        int k0 = kt * 64, r0 = rt * 32;
        for (int u = tid; u < 2048; u += 256) {
            int row = u >> 5, c = u & 31;
            tile[row * 33 + c] = A[(size_t)(k0 + row) * RANK + r0 + c];
        }
        __syncthreads();
        for (int u = tid; u < 2048; u += 256) {
            int rr = u >> 6, k = u & 63;
            at[(size_t)(r0 + rr) * IN_F + k0 + k] = f2bf(tile[k * 33 + rr]);
        }
    } else if (bid < 768) {
        int b2 = bid - 512, rt = b2 >> 7, ot = b2 & 127;
        int r0 = rt * 64, o0 = ot * 32;
        for (int u = tid; u < 2048; u += 256) {
            int row = u >> 5, c = u & 31;
            tile[row * 33 + c] = B[(size_t)(r0 + row) * OUT_F + o0 + c];
        }
        __syncthreads();
        for (int u = tid; u < 2048; u += 256) {
            int oo = u >> 6, k = u & 63;
            bt[(size_t)(o0 + oo) * RANK + r0 + k] = f2bf(tile[k * 33 + oo]);
        }
    } else {
        int idx = (bid - 768) * 256 + tid;
        f32x4 z = {0.f, 0.f, 0.f, 0.f};
        if (idx < 131072) ((f32x4*)outz)[idx] = z;
        else if (idx < 131072 + 4096) ((f32x4*)y)[idx - 131072] = z;
    }
}

// ---- y = xb @ At^T (M=128, N=RANK=128, K=4096), k-split 16, atomic f32
__global__ __launch_bounds__(512) void lora_y_kernel(
    const u16* __restrict__ xb, const u16* __restrict__ at,
    float* __restrict__ y) {
    int tid = threadIdx.x, lane = tid & 63, wid = tid >> 6;
    int wm = wid >> 1, wn = wid & 1;
    int col = lane & 15, kg = lane >> 4;
    int rt = blockIdx.x & 3, kq = blockIdx.x >> 2;
    int r = rt * 32 + wn * 16 + col;
    int k0 = kq * 256;
    const u16* xp0 = xb + (size_t)(wm * 32 + col) * IN_F + k0 + kg * 8;
    const u16* xp1 = xp0 + (size_t)16 * IN_F;
    const u16* ap = at + (size_t)r * IN_F + k0 + kg * 8;
    f32x4 acc0 = {0.f, 0.f, 0.f, 0.f}, acc1 = {0.f, 0.f, 0.f, 0.f};
    #pragma unroll
    for (int k = 0; k < 256; k += 32) {
        short8 bf = *(const short8*)(ap + k);
        short8 a0 = *(const short8*)(xp0 + k);
        short8 a1 = *(const short8*)(xp1 + k);
        acc0 = __builtin_amdgcn_mfma_f32_16x16x32_bf16(a0, bf, acc0, 0, 0, 0);
        acc1 = __builtin_amdgcn_mfma_f32_16x16x32_bf16(a1, bf, acc1, 0, 0, 0);
    }
    int rbase = wm * 32 + kg * 4;
    #pragma unroll
    for (int j = 0; j < 4; ++j) {
        atomicAdd(&y[(rbase + j) * RANK + r], acc0[j]);
        atomicAdd(&y[(rbase + j + 16) * RANK + r], acc1[j]);
    }
}

// ---- main: BM=128, BN=32, ksplit=4 -> 512 blocks x 512 thr (8 waves)
// wq staged via global_load_lds (linear dest, pre-swizzled src), x direct L2
#define KCHUNK 1024
#define KSTEP 64
#define NSTEPS 16

__global__ __launch_bounds__(512) void main_kernel(
    const u16* __restrict__ xb, const int* __restrict__ wq,
    const float* __restrict__ scale, const float* __restrict__ bias,
    const float* __restrict__ y, const u16* __restrict__ bt,
    float* __restrict__ out) {
    __shared__ int lds[2][2048];  // 2 x 8KB: [32 o-rows][64 k-ints]
    int tid = threadIdx.x, lane = tid & 63, wid = tid >> 6;
    int wm = wid >> 1, wn = wid & 1;
    int col = lane & 15, kg = lane >> 4;
    int nb = blockIdx.x & 127, kq = blockIdx.x >> 7;
    int o0 = nb * 32, k0 = kq * KCHUNK;
    int o = o0 + wn * 16 + col;

    // staging: thread t -> lds bytes [t*16, t*16+16), row = t>>4.
    // inverse-swizzled global source: k-int = 4*((t&15) ^ (row&7))
    int srow = tid >> 4;
    int skint = 4 * ((tid & 15) ^ (srow & 7));
    const int* sp = wq + (size_t)(o0 + srow) * IN_F + k0 + skint;

    const u16* xp0 = xb + (size_t)(wm * 32 + col) * IN_F + k0 + kg * 8;
    const u16* xp1 = xp0 + (size_t)16 * IN_F;

    int brow = wn * 16 + col;          // o-row this lane reads
    int brbyte = brow * 256;
    int bmask = (brow & 7) << 4;       // XOR swizzle on read

    f32x4 acc0 = {0.f, 0.f, 0.f, 0.f}, acc1 = {0.f, 0.f, 0.f, 0.f};

    auto stage = [&](int buf, int t) {
        __builtin_amdgcn_global_load_lds(
            (gas_ptr)(const void*)(sp + t * KSTEP),
            (las_ptr)(void*)&lds[buf][wid * 256], 16, 0, 0);
    };

    stage(0, 0);
    int cur = 0;
    for (int t = 0; t < NSTEPS; ++t) {
        __syncthreads();                       // buf[cur] staged (vmcnt0+bar)
        if (t + 1 < NSTEPS) stage(cur ^ 1, t + 1);
        const char* bb = (const char*)&lds[cur][0] + brbyte;
        int koff = t * KSTEP;
        #pragma unroll
        for (int ks = 0; ks < 2; ++ks) {
            int b0 = ks * 128 + kg * 32;
            int4 wa = *(const int4*)(bb + (b0 ^ bmask));
            int4 wb = *(const int4*)(bb + ((b0 + 16) ^ bmask));
            union { u32 u[4]; short8 s; } bf;
            bf.u[0] = packi(wa.x, wa.y); bf.u[1] = packi(wa.z, wa.w);
            bf.u[2] = packi(wb.x, wb.y); bf.u[3] = packi(wb.z, wb.w);
            short8 a0 = *(const short8*)(xp0 + koff + ks * 32);
            short8 a1 = *(const short8*)(xp1 + koff + ks * 32);
            acc0 = __builtin_amdgcn_mfma_f32_16x16x32_bf16(a0, bf.s, acc0, 0, 0, 0);
            acc1 = __builtin_amdgcn_mfma_f32_16x16x32_bf16(a1, bf.s, acc1, 0, 0, 0);
        }
        __syncthreads();                       // readers done before rewrite
        cur ^= 1;
    }

    float s = scale[o];
    #pragma unroll
    for (int j = 0; j < 4; ++j) { acc0[j] *= s; acc1[j] *= s; }

    if (kq == 0) {  // LoRA + bias added once
        const float* yp0 = y + (size_t)(wm * 32 + col) * RANK + kg * 8;
        const float* yp1 = yp0 + 16 * RANK;
        const u16* bp = bt + (size_t)o * RANK + kg * 8;
        #pragma unroll
        for (int ks = 0; ks < RANK; ks += 32) {
            f32x4 ya = *(const f32x4*)(yp0 + ks);
            f32x4 yb = *(const f32x4*)(yp0 + ks + 4);
            f32x4 yc = *(const f32x4*)(yp1 + ks);
            f32x4 yd = *(const f32x4*)(yp1 + ks + 4);
            union { u32 u[4]; short8 s; } af0, af1;
            af0.u[0] = packf(ya[0], ya[1]); af0.u[1] = packf(ya[2], ya[3]);
            af0.u[2] = packf(yb[0], yb[1]); af0.u[3] = packf(yb[2], yb[3]);
            af1.u[0] = packf(yc[0], yc[1]); af1.u[1] = packf(yc[2], yc[3]);
            af1.u[2] = packf(yd[0], yd[1]); af1.u[3] = packf(yd[2], yd[3]);
            short8 bfr = *(const short8*)(bp + ks);
            acc0 = __builtin_amdgcn_mfma_f32_16x16x32_bf16(af0.s, bfr, acc0, 0, 0, 0);
            acc1 = __builtin_amdgcn_mfma_f32_16x16x32_bf16(af1.s, bfr, acc1, 0, 0, 0);
        }
        float bv = bias[o];
        #pragma unroll
        for (int j = 0; j < 4; ++j) { acc0[j] += bv; acc1[j] += bv; }
    }

    int rbase = wm * 32 + kg * 4;
    float* op = out + (size_t)rbase * OUT_F + o;
    #pragma unroll
    for (int j = 0; j < 4; ++j) {
        atomicAdd(op + (size_t)j * OUT_F, acc0[j]);
        atomicAdd(op + (size_t)(j + 16) * OUT_F, acc1[j]);
    }
}

extern "C" void kernel_launch(void* const* d_in, const int* in_sizes, int n_in,
                              void* d_out, int out_size, void* d_ws, size_t ws_size,
                              hipStream_t stream) {
    const float* x = (const float*)d_in[0];
    const int* wq = (const int*)d_in[1];
    const float* scale = (const float*)d_in[2];
    const float* A = (const float*)d_in[3];
    const float* B = (const float*)d_in[4];
    const float* bias = (const float*)d_in[5];
    float* out = (float*)d_out;

    char* ws = (char*)d_ws;
    float* y = (float*)(ws + WS_Y);
    u16* xb = (u16*)(ws + WS_XB);
    u16* bt = (u16*)(ws + WS_BT);
    u16* at = (u16*)(ws + WS_AT);

    prep0_kernel<<<1296, 256, 0, stream>>>(x, A, B, out, y, xb, at, bt);
    lora_y_kernel<<<64, 512, 0, stream>>>(xb, at, y);
    main_kernel<<<512, 512, 0, stream>>>(xb, wq, scale, bias, y, bt, out);
}